// Round 7
// baseline (1726.240 us; speedup 1.0000x reference)
//
#include <hip/hip_runtime.h>
#include <hip/hip_bf16.h>

#define NN 40000      // nodes
#define NE 150000     // edges per type
#define HF 512        // H*D
#define NHEAD 4

typedef __bf16 bf16x8 __attribute__((ext_vector_type(8)));
typedef float floatx4 __attribute__((ext_vector_type(4)));
typedef __hip_bfloat16 bf16;
typedef unsigned short u16;

__device__ __forceinline__ float bf2f(bf16 v) { return __bfloat162float(v); }
__device__ __forceinline__ float u2f(u16 v) { return __uint_as_float(((unsigned)v) << 16); }

// async global->LDS DMA, 16B per lane. ldsbase must be wave-uniform;
// HW writes lane i's 16B at ldsbase + i*16 (linear, no per-lane scatter).
__device__ __forceinline__ void gload16(const void* g, void* l) {
    __builtin_amdgcn_global_load_lds(
        (const __attribute__((address_space(1))) void*)g,
        (__attribute__((address_space(3))) void*)l, 16, 0, 0);
}

__device__ __forceinline__ void store_c(float* p, float v) {
    __builtin_nontemporal_store(v, p);   // final fp32 out: don't pollute L2
}
__device__ __forceinline__ void store_c(bf16* p, float v) { *p = __float2bfloat16(v); }

// ---------------- cast fp32 -> bf16, elementwise (8/thread, 16B stores) -----
__global__ void cast_k(const float* __restrict__ in, bf16* __restrict__ out, int n) {
    int i = (blockIdx.x * blockDim.x + threadIdx.x) * 8;
    if (i + 7 < n) {
        float4 v0 = *(const float4*)(in + i);
        float4 v1 = *(const float4*)(in + i + 4);
        union { uint4 u; u16 s[8]; } w;
        float fv[8] = {v0.x, v0.y, v0.z, v0.w, v1.x, v1.y, v1.z, v1.w};
#pragma unroll
        for (int j = 0; j < 8; j++) {
            bf16 b = __float2bfloat16(fv[j]);
            w.s[j] = *(const u16*)&b;
        }
        *(uint4*)(out + i) = w.u;
    } else {
        for (int j = i; j < n; j++) out[j] = __float2bfloat16(in[j]);
    }
}

// ---------------- transpose+cast: WT[n*K+k] = bf16(W[k*N+n]) ----------------
__global__ void transpose_k(const float* __restrict__ W, bf16* __restrict__ WT,
                            int K, int Nn) {
    __shared__ float tile[32][33];
    int n0 = blockIdx.x * 32, k0 = blockIdx.y * 32;
    int tx = threadIdx.x, ty = threadIdx.y;
    int n = n0 + tx, k = k0 + ty;
    if (n < Nn && k < K) tile[ty][tx] = W[(size_t)k * Nn + n];
    __syncthreads();
    int nn = n0 + ty, kk = k0 + tx;
    if (nn < Nn && kk < K) WT[(size_t)nn * K + kk] = __float2bfloat16(tile[tx][ty]);
}

// ---------------- GEMM: C[M,Nn] = A[M,K] * BT[Nn,K]^T ----------------
// 128x128 tile, BK=32, 4 waves (2x2), each wave 64x64 = 4x4 frags 16x16x32.
// Staging: global_load_lds width=16 into LINEAR TRIPLE-buffered [128][32] LDS.
// Bank-conflict-free via source-side XOR swizzle (chunk c ^ ((row>>1)&3)).
// T4 counted-vmcnt pipeline: 2 tiles prefetched ahead; raw s_barrier with
// explicit "s_waitcnt vmcnt(4) lgkmcnt(0)" keeps the newest tile's 4 loads
// in flight ACROSS the barrier (never drain to 0 mid-loop).
// NOTE: __syncthreads() is deliberately NOT used in the K-loop — the compiler
// legalizes it with a full vmcnt(0) drain, which is the stall being removed.
// Buffer i is overwritten only 3 iterations later (one barrier after all its
// ds_reads drained by lgkmcnt(0)) -> no race.
// grid: (ntiles, mtiles) — blockIdx.x walks N so consecutive blocks share the
// A row-panel; bijective XCD swizzle keeps panel-sharers on one XCD L2.
template <typename TOUT, bool HAS_BIAS>
__global__ __launch_bounds__(256) void gemm_k(const bf16* __restrict__ A,
                                              const bf16* __restrict__ BT,
                                              TOUT* __restrict__ C,
                                              const float* __restrict__ bias,
                                              int M, int Nn, int K) {
    __shared__ __align__(16) unsigned short As[3][128][32];
    __shared__ __align__(16) unsigned short Bs[3][128][32];

    // bijective XCD swizzle (m204 form; handles nwg % 8 != 0)
    const int nwg = gridDim.x * gridDim.y;
    const int orig = blockIdx.y * gridDim.x + blockIdx.x;
    const int qq = nwg >> 3, r8 = nwg & 7;
    const int xcd = orig & 7, loc = orig >> 3;
    const int swz = (xcd < r8 ? xcd * (qq + 1) : r8 * (qq + 1) + (xcd - r8) * qq) + loc;
    const int ntile = swz % gridDim.x;
    const int mtile = swz / gridDim.x;
    const int m0 = mtile * 128;
    const int n0 = ntile * 128;

    const int t = threadIdx.x;
    const int lane = t & 63;
    const int wave = t >> 6;
    const int wm = wave >> 1, wn = wave & 1;
    const int q = lane >> 4, r = lane & 15;

    // staging geometry: wave w stages rows [w*32, w*32+32) in 2 rounds of 16
    // rows (64 lanes x 16B = 1KB linear). Lane l -> slot row w*32+(l>>2)
    // (+16 round 1), slot chunk l&3. Source chunk = (l&3) ^ ((srow>>1)&3).
    const int srow = wave * 32 + (lane >> 2);
    const int scol = ((lane & 3) ^ ((srow >> 1) & 3)) * 8;  // element offset
    int ar0 = m0 + srow;        if (ar0 >= M)  ar0 = M - 1;
    int ar1 = m0 + srow + 16;   if (ar1 >= M)  ar1 = M - 1;
    int br0 = n0 + srow;        if (br0 >= Nn) br0 = Nn - 1;
    int br1 = n0 + srow + 16;   if (br1 >= Nn) br1 = Nn - 1;
    const unsigned short* Ag0 = (const unsigned short*)A + (size_t)ar0 * K + scol;
    const unsigned short* Ag1 = (const unsigned short*)A + (size_t)ar1 * K + scol;
    const unsigned short* Bg0 = (const unsigned short*)BT + (size_t)br0 * K + scol;
    const unsigned short* Bg1 = (const unsigned short*)BT + (size_t)br1 * K + scol;

    // fragment-read chunk offsets (elements), same XOR as staging
    const int rchunk = (q ^ ((r >> 1) & 3)) * 8;

    unsigned short* Abase = &As[0][0][0] + wave * 1024;  // + buf*4096
    unsigned short* Bbase = &Bs[0][0][0] + wave * 1024;

    auto STAGE = [&](int kk, int buf) {
        const int k1 = kk << 5;
        unsigned short* Al = Abase + buf * 4096;
        unsigned short* Bl = Bbase + buf * 4096;
        gload16(Ag0 + k1, Al);
        gload16(Ag1 + k1, Al + 512);
        gload16(Bg0 + k1, Bl);
        gload16(Bg1 + k1, Bl + 512);
    };

    floatx4 acc[4][4] = {};
    const int nt = K >> 5;   // >= 16 here
    // prologue: 2 tiles in flight
    STAGE(0, 0);
    STAGE(1, 1);
    asm volatile("s_waitcnt vmcnt(4)" ::: "memory");   // tile 0 landed
    __builtin_amdgcn_s_barrier();
    int cur = 0;
    for (int tt = 0; tt < nt; tt++) {
        const bool pf = (tt + 2) < nt;
        if (pf) {
            int nb = cur + 2; if (nb >= 3) nb -= 3;
            STAGE(tt + 2, nb);
        }
        bf16x8 a[4], b[4];
#pragma unroll
        for (int i = 0; i < 4; i++)
            a[i] = *(const bf16x8*)&As[cur][wm * 64 + i * 16 + r][rchunk];
#pragma unroll
        for (int j = 0; j < 4; j++)
            b[j] = *(const bf16x8*)&Bs[cur][wn * 64 + j * 16 + r][rchunk];
#pragma unroll
        for (int i = 0; i < 4; i++)
#pragma unroll
            for (int j = 0; j < 4; j++)
                acc[i][j] = __builtin_amdgcn_mfma_f32_16x16x32_bf16(a[i], b[j], acc[i][j], 0, 0, 0);
        // next tile (tt+1) must be landed before anyone reads it after the
        // barrier; keep the freshly-issued tile (tt+2) in flight.
        if (pf) asm volatile("s_waitcnt vmcnt(4) lgkmcnt(0)" ::: "memory");
        else    asm volatile("s_waitcnt vmcnt(0) lgkmcnt(0)" ::: "memory");
        __builtin_amdgcn_s_barrier();
        cur = (cur == 2) ? 0 : cur + 1;
    }

    // hoisted bias (4 columns per thread)
    float bv4[4] = {0.f, 0.f, 0.f, 0.f};
    if (HAS_BIAS) {
#pragma unroll
        for (int j = 0; j < 4; j++) {
            int col = n0 + wn * 64 + j * 16 + r;
            if (col < Nn) bv4[j] = bias[col];
        }
    }
#pragma unroll
    for (int i = 0; i < 4; i++)
#pragma unroll
        for (int j = 0; j < 4; j++)
#pragma unroll
            for (int rr = 0; rr < 4; rr++) {
                int row = m0 + wm * 64 + i * 16 + q * 4 + rr;
                int col = n0 + wn * 64 + j * 16 + r;
                if (row < M && col < Nn) {
                    float v = acc[i][j][rr];
                    if (HAS_BIAS) v += bv4[j];
                    store_c(&C[(size_t)row * Nn + col], v);
                }
            }
}

// ---------------- attention logits, both types fused ------------------------
// featb: [NN][1024] bf16 (cols [0,512)=type0, [512,1024)=type1).
// One wave per node; lane covers 16 elems: type=lane>>5, head=(lane>>3)&3,
// ld=lane&7. el/er layout: [2][NN][NHEAD] fp32.
__global__ void attn_k(const bf16* __restrict__ featb, const float* __restrict__ al_l,
                       const float* __restrict__ ar_l, float* __restrict__ el,
                       float* __restrict__ er) {
    int lane = threadIdx.x & 63;
    int wave = threadIdx.x >> 6;
    int node = blockIdx.x * 4 + wave;
    if (node >= NN) return;
    int tt = lane >> 5, h = (lane >> 3) & 3, ld = lane & 7;
    const u16* fp = (const u16*)featb + (size_t)node * 1024 + lane * 16;
    union { uint4 v; u16 s[8]; } u0, u1;
    u0.v = *(const uint4*)fp;
    u1.v = *(const uint4*)(fp + 8);
    const float* alp = al_l + tt * HF + h * 128 + ld * 16;
    const float* arp = ar_l + tt * HF + h * 128 + ld * 16;
    float sl = 0.f, sr = 0.f;
#pragma unroll
    for (int j = 0; j < 8; j++) {
        float f = u2f(u0.s[j]);
        sl += f * alp[j];
        sr += f * arp[j];
    }
#pragma unroll
    for (int j = 0; j < 8; j++) {
        float f = u2f(u1.s[j]);
        sl += f * alp[8 + j];
        sr += f * arp[8 + j];
    }
#pragma unroll
    for (int off = 4; off >= 1; off >>= 1) {
        sl += __shfl_down(sl, off, 8);
        sr += __shfl_down(sr, off, 8);
    }
    if (ld == 0) {
        size_t o = (size_t)tt * NN * NHEAD + node * NHEAD + h;
        el[o] = sl;
        er[o] = sr;
    }
}

// ---------------- CSR build: degree histogram ----------------
__global__ void deg_count_k(const int* __restrict__ dst, int* __restrict__ deg) {
    int e = blockIdx.x * blockDim.x + threadIdx.x;
    if (e < NE) atomicAdd(&deg[dst[e]], 1);
}

// ---------------- CSR build: exclusive scan (single block, 1024 thr) --------
__global__ void scan_k(const int* __restrict__ deg, int* __restrict__ off) {
    __shared__ int part[1024];
    const int CH = (NN + 1023) >> 10;  // elements per thread
    int t = threadIdx.x;
    int base = t * CH;
    int s = 0;
    for (int i = 0; i < CH; i++) {
        int idx = base + i;
        if (idx < NN) s += deg[idx];
    }
    part[t] = s;
    __syncthreads();
    for (int d = 1; d < 1024; d <<= 1) {
        int v = (t >= d) ? part[t - d] : 0;
        __syncthreads();
        part[t] += v;
        __syncthreads();
    }
    int run = (t == 0) ? 0 : part[t - 1];
    for (int i = 0; i < CH; i++) {
        int idx = base + i;
        if (idx < NN) {
            off[idx] = run;
            run += deg[idx];
        } else if (idx == NN) {
            off[NN] = run;
        }
    }
}

// ---------------- CSR build: fill sorted src list ----------------
__global__ void fill_k(const int* __restrict__ src, const int* __restrict__ dst,
                       const int* __restrict__ off, int* __restrict__ cur,
                       int* __restrict__ csrc) {
    int e = blockIdx.x * blockDim.x + threadIdx.x;
    if (e >= NE) return;
    int d = dst[e];
    int p = atomicAdd(&cur[d], 1);
    csrc[off[d] + p] = src[e];
}

// ---------------- fused gather, both types: softmax + aggregate + bias + act
// One wave per dst node; lane owns 8 contiguous elems of the 512-row (h=lane>>4).
// For each type: online max/exp-sum over CSR, then weighted bf16 gather;
// per-type bias+activation applied, summed across types, single bf16 write.
__global__ __launch_bounds__(256) void gather_k(
    const int* __restrict__ off0, const int* __restrict__ csrc0,
    const int* __restrict__ off1, const int* __restrict__ csrc1,
    const float* __restrict__ el, const float* __restrict__ er,
    const bf16* __restrict__ featb, const float* __restrict__ bb_l,
    bf16* __restrict__ hout, int act) {
    int lane = threadIdx.x & 63;
    int wave = threadIdx.x >> 6;
    int d = blockIdx.x * 4 + wave;
    if (d >= NN) return;
    int h = lane >> 4;
    const int* offs[2] = {off0, off1};
    const int* csrcs[2] = {csrc0, csrc1};

    float out[8] = {};
#pragma unroll
    for (int tt = 0; tt < 2; tt++) {
        const int* off = offs[tt];
        const int* csrc = csrcs[tt];
        const float* elt = el + (size_t)tt * NN * NHEAD;
        int o0 = off[d], o1 = off[d + 1];
        float erd = er[(size_t)tt * NN * NHEAD + d * NHEAD + h];
        // online segment max + exp-sum
        float m = -3.0e38f, sum = 0.f;
        for (int i = o0; i < o1; i++) {
            int s = csrc[i];
            float lg = elt[s * NHEAD + h] + erd;
            lg = lg > 0.f ? lg : 0.2f * lg;
            float mn = fmaxf(m, lg);
            sum = sum * __expf(m - mn) + __expf(lg - mn);
            m = mn;
        }
        float inv = sum > 0.f ? 1.f / sum : 0.f;
        // weighted gather (bf16 feat rows)
        float acc[8] = {};
        for (int i = o0; i < o1; i++) {
            int s = csrc[i];
            float lg = elt[s * NHEAD + h] + erd;
            lg = lg > 0.f ? lg : 0.2f * lg;
            float a = __expf(lg - m) * inv;
            const u16* fp = (const u16*)featb + (size_t)s * 1024 + tt * HF + lane * 8;
            union { uint4 v; u16 s8[8]; } u;
            u.v = *(const uint4*)fp;
#pragma unroll
            for (int j = 0; j < 8; j++) acc[j] += u2f(u.s8[j]) * a;
        }
        // per-type bias + activation, accumulate across types
        const float* bp = bb_l + tt * HF + lane * 8;
        float4 b0 = *(const float4*)bp;
        float4 b1 = *(const float4*)(bp + 4);
        float bv[8] = {b0.x, b0.y, b0.z, b0.w, b1.x, b1.y, b1.z, b1.w};
#pragma unroll
        for (int j = 0; j < 8; j++) {
            float v = acc[j] + bv[j];
            if (act) v = v > 0.f ? v : 0.01f * v;
            out[j] += v;
        }
    }
    union { uint4 v; u16 s[8]; } outw;
#pragma unroll
    for (int j = 0; j < 8; j++) {
        bf16 ob = __float2bfloat16(out[j]);
        outw.s[j] = *(const u16*)&ob;
    }
    *(uint4*)((u16*)hout + (size_t)d * HF + lane * 8) = outw.v;
}

extern "C" void kernel_launch(void* const* d_in, const int* in_sizes, int n_in,
                              void* d_out, int out_size, void* d_ws, size_t ws_size,
                              hipStream_t stream) {
    const float* x = (const float*)d_in[0];
    const int* srcs[2] = {(const int*)d_in[1], (const int*)d_in[3]};
    const int* dsts[2] = {(const int*)d_in[2], (const int*)d_in[4]};
    const float* W[3] = {(const float*)d_in[5], (const float*)d_in[9], (const float*)d_in[13]};
    const float* al[3] = {(const float*)d_in[6], (const float*)d_in[10], (const float*)d_in[14]};
    const float* ar[3] = {(const float*)d_in[7], (const float*)d_in[11], (const float*)d_in[15]};
    const float* bb[3] = {(const float*)d_in[8], (const float*)d_in[12], (const float*)d_in[16]};
    const float* Wout = (const float*)d_in[17];
    const float* bout = (const float*)d_in[18];

    // workspace layout (~95 MB)
    char* ws = (char*)d_ws;
    size_t off = 0;
    auto walloc = [&](size_t bytes) {
        void* p = ws + off;
        off = (off + bytes + 255) & ~(size_t)255;
        return p;
    };
    bf16* h0 = (bf16*)walloc((size_t)NN * HF * 2);
    bf16* h1 = (bf16*)walloc((size_t)NN * HF * 2);
    float* el = (float*)walloc((size_t)2 * NN * NHEAD * 4);
    float* er = (float*)walloc((size_t)2 * NN * NHEAD * 4);
    bf16* WT = (bf16*)walloc((size_t)2983 * 512 * 2);
    bf16* WT2 = (bf16*)walloc((size_t)1024 * 1024 * 2);
    int* deg = (int*)walloc((size_t)NN * 4);
    int* cur = (int*)walloc((size_t)NN * 4);
    int* offs[2];
    int* csrc[2];
    for (int t = 0; t < 2; t++) {
        offs[t] = (int*)walloc((size_t)(NN + 1) * 4);
        csrc[t] = (int*)walloc((size_t)NE * 4);
    }

    // dead regions of d_out used as scratch (out is fp32, 477 MB; final GEMM
    // overwrites everything). xb: [81.92, 163.84) MB, featb: [163.84, 245.8) MB
    bf16* xb = (bf16*)((char*)d_out + (size_t)NN * HF * 4);
    bf16* featb = (bf16*)((char*)d_out + (size_t)NN * HF * 4 + (size_t)NN * 1024 * 2);

    // cast x (fp32 -> bf16) once
    cast_k<<<(NN * 1024 / 8 + 255) / 256, 256, 0, stream>>>(x, xb, NN * 1024);

    // build dst-CSR per edge type (reused across all 3 layers)
    const int EB = (NE + 255) / 256;
    for (int t = 0; t < 2; t++) {
        hipMemsetAsync(deg, 0, (size_t)NN * 4, stream);
        hipMemsetAsync(cur, 0, (size_t)NN * 4, stream);
        deg_count_k<<<EB, 256, 0, stream>>>(dsts[t], deg);
        scan_k<<<1, 1024, 0, stream>>>(deg, offs[t]);
        fill_k<<<EB, 256, 0, stream>>>(srcs[t], dsts[t], offs[t], cur, csrc[t]);
    }

    const int MT = (NN + 127) / 128;  // 313 M-tiles

    for (int l = 0; l < 3; l++) {
        const int K = (l == 0) ? 1024 : 512;
        const bf16* hin = (l == 0) ? xb : ((l == 1) ? h0 : h1);
        bf16* hout = (l == 0) ? h0 : ((l == 1) ? h1 : h0);
        const int act = (l < 2) ? 1 : 0;
        // both types' weights -> WT2 [1024][K]
        for (int t = 0; t < 2; t++)
            transpose_k<<<dim3(512 / 32, K / 32), dim3(32, 32), 0, stream>>>(
                W[l] + (size_t)t * K * 512, WT2 + (size_t)t * 512 * K, K, 512);
        // featb[NN][1024] = hin @ [W_t0 | W_t1]   (bf16 out)
        gemm_k<bf16, false><<<dim3(1024 / 128, MT), 256, 0, stream>>>(
            hin, WT2, featb, nullptr, NN, 1024, K);
        // logits for both types
        attn_k<<<NN / 4, 256, 0, stream>>>(featb, al[l], ar[l], el, er);
        // fused both-type edge-softmax + aggregate + bias + act + type-sum
        gather_k<<<NN / 4, 256, 0, stream>>>(offs[0], csrc[0], offs[1], csrc[1],
                                             el, er, featb, bb[l], hout, act);
    }

    // final projection: out = h @ Wout + bout   [40000 x 2983] fp32
    transpose_k<<<dim3((2983 + 31) / 32, 512 / 32), dim3(32, 32), 0, stream>>>(
        Wout, WT, 512, 2983);
    gemm_k<float, true><<<dim3((2983 + 127) / 128, MT), 256, 0, stream>>>(
        h0, WT, (float*)d_out, bout, NN, 2983, 512);
}